// Round 1
// baseline (313.816 us; speedup 1.0000x reference)
//
#include <hip/hip_runtime.h>

typedef __attribute__((ext_vector_type(8))) short short8;
typedef __attribute__((ext_vector_type(4))) float f32x4;

// ---------- helpers ----------
__device__ __forceinline__ unsigned short f2bf(float f) {
  unsigned u = __builtin_bit_cast(unsigned, f);
  u += 0x7fffu + ((u >> 16) & 1u);   // RNE
  return (unsigned short)(u >> 16);
}

#define GLDS16(g, l)                                                          \
  __builtin_amdgcn_global_load_lds(                                           \
      (const __attribute__((address_space(1))) void*)(g),                     \
      (__attribute__((address_space(3))) void*)(l), 16, 0, 0)

// ---------- cast x (fp32 -> bf16), vectorized ----------
__global__ void cast_x_bf16(const float4* __restrict__ in,
                            ushort4* __restrict__ out, int n4) {
  int i = blockIdx.x * blockDim.x + threadIdx.x;
  if (i >= n4) return;
  float4 v = in[i];
  ushort4 o;
  o.x = f2bf(v.x); o.y = f2bf(v.y); o.z = f2bf(v.z); o.w = f2bf(v.w);
  out[i] = o;
}

// ---------- transpose + convert: in fp32 [K][N] -> out bf16 [N][K] ----------
__global__ void transpose_cvt(const float* __restrict__ in,
                              unsigned short* __restrict__ out, int K, int N) {
  __shared__ float tile[32][33];
  int n0 = blockIdx.x * 32, k0 = blockIdx.y * 32;
  int tx = threadIdx.x, ty = threadIdx.y;  // block (32,8)
#pragma unroll
  for (int i = 0; i < 4; ++i)
    tile[ty + 8 * i][tx] = in[(size_t)(k0 + ty + 8 * i) * N + n0 + tx];
  __syncthreads();
#pragma unroll
  for (int i = 0; i < 4; ++i)
    out[(size_t)(n0 + ty + 8 * i) * K + k0 + tx] = f2bf(tile[tx][ty + 8 * i]);
}

// ---------- GEMM: C[M][N] = A[M][K](bf16) * Bt[N][K](bf16)^T ----------
// m97 structure: 128x128 tile, BK=64, 4 waves (2x2 of 64x64), global_load_lds w=16.
// EPI==0: QKV epilogue (col<1024 -> Q bf16 [row][col]; col<1088 -> K bf16 [row][64];
//         else V TRANSPOSED bf16 [b][d][t]).  EPI==1: plain fp32 C.
template <int EPI>
__global__ __launch_bounds__(256) void gemm_bt(
    const unsigned short* __restrict__ A, const unsigned short* __restrict__ Bt,
    unsigned short* __restrict__ Cq, unsigned short* __restrict__ Ck,
    unsigned short* __restrict__ Cv, float* __restrict__ Cf, int N, int K) {
  __shared__ __align__(16) unsigned short As[128 * 64];
  __shared__ __align__(16) unsigned short Bs[128 * 64];
  const int tid = threadIdx.x;
  const int w = tid >> 6, lane = tid & 63;
  const int m0 = blockIdx.y * 128, n0 = blockIdx.x * 128;
  const int wm = (w >> 1) * 64, wn = (w & 1) * 64;
  const int g = lane >> 4, c = lane & 15;
  const int lr = lane >> 3, lc = (lane & 7) * 8;

  f32x4 acc[4][4] = {};

  for (int k0 = 0; k0 < K; k0 += 64) {
#pragma unroll
    for (int i = 0; i < 4; ++i) {
      int ci = w * 4 + i;  // 1KB chunk: rows 8ci..8ci+7
      GLDS16(A + (size_t)(m0 + ci * 8 + lr) * K + k0 + lc, As + ci * 512);
      GLDS16(Bt + (size_t)(n0 + ci * 8 + lr) * K + k0 + lc, Bs + ci * 512);
    }
    __syncthreads();
#pragma unroll
    for (int kk = 0; kk < 2; ++kk) {
      const int col = kk * 32 + g * 8;
      short8 av[4], bv[4];
#pragma unroll
      for (int mi = 0; mi < 4; ++mi)
        av[mi] = *(const short8*)(As + (wm + mi * 16 + c) * 64 + col);
#pragma unroll
      for (int ni = 0; ni < 4; ++ni)
        bv[ni] = *(const short8*)(Bs + (wn + ni * 16 + c) * 64 + col);
#pragma unroll
      for (int mi = 0; mi < 4; ++mi)
#pragma unroll
        for (int ni = 0; ni < 4; ++ni)
          acc[mi][ni] = __builtin_amdgcn_mfma_f32_16x16x32_bf16(
              av[mi], bv[ni], acc[mi][ni], 0, 0, 0);
    }
    __syncthreads();
  }

#pragma unroll
  for (int mi = 0; mi < 4; ++mi) {
#pragma unroll
    for (int ni = 0; ni < 4; ++ni) {
      f32x4 a = acc[mi][ni];
      const int col = n0 + wn + ni * 16 + c;
#pragma unroll
      for (int r = 0; r < 4; ++r) {
        const int row = m0 + wm + mi * 16 + g * 4 + r;
        float v = a[r];
        if (EPI == 0) {
          if (col < 1024)
            Cq[(size_t)row * 1024 + col] = f2bf(v);
          else if (col < 1088)
            Ck[(size_t)row * 64 + (col - 1024)] = f2bf(v);
          else  // V transposed: [b][d][t]
            Cv[((size_t)(row >> 11) * 64 + (col - 1088)) * 2048 + (row & 2047)] =
                f2bf(v);
        } else {
          Cf[(size_t)row * N + col] = v;
        }
      }
    }
  }
}

// ---------- causal multi-query flash attention ----------
// grid (32 qtiles, 16 heads, 4 batch), 256 threads = 4 waves x 16 q-rows.
// Q [8192][1024] bf16 (head h at cols h*64..); K [b*2048+t][64]; Vt [b][64][2048].
// K/V LDS tiles XOR-swizzled (G4): source pre-swizzle + swizzled ds_read.
__global__ __launch_bounds__(256) void attn_mqa(
    const unsigned short* __restrict__ Q, const unsigned short* __restrict__ Kb,
    const unsigned short* __restrict__ Vt, unsigned short* __restrict__ Oc) {
  __shared__ __align__(16) unsigned short Kl[64 * 64];
  __shared__ __align__(16) unsigned short Vl[64 * 64];
  __shared__ __align__(16) unsigned short Pl[4][16 * 72];
  const int tid = threadIdx.x;
  const int w = tid >> 6, lane = tid & 63;
  const int qt = blockIdx.x, h = blockIdx.y, b = blockIdx.z;
  const int q0 = qt * 64;
  const int qb = q0 + w * 16;          // this wave's first q row (global t)
  const int g = lane >> 4, c = lane & 15;
  const int lr = lane >> 3;
  const int lcs = ((lane & 7) ^ (lr & 7)) * 8;  // swizzled source col (shorts)
  const int swr = (c & 7) * 8;                  // read-side xor (shorts)

  // Q fragments in registers (A-operand layout: row=c, k=g*8+j)
  short8 qf[2];
#pragma unroll
  for (int kk = 0; kk < 2; ++kk)
    qf[kk] = *(const short8*)(Q + (size_t)(b * 2048 + qb + c) * 1024 + h * 64 +
                              kk * 32 + g * 8);

  f32x4 po[4] = {};
  float mrow[4], lrow[4];
#pragma unroll
  for (int r = 0; r < 4; ++r) { mrow[r] = -1e30f; lrow[r] = 0.f; }

  unsigned short* pw = Pl[w];

  for (int it = 0; it <= qt; ++it) {
    const int kv0 = it * 64;
#pragma unroll
    for (int i = 0; i < 2; ++i) {
      int ci = w * 2 + i;  // rows 8ci..8ci+7 of the 64-row tile
      GLDS16(Kb + (size_t)(b * 2048 + kv0 + ci * 8 + lr) * 64 + lcs,
             Kl + ci * 512);
      GLDS16(Vt + ((size_t)b * 64 + ci * 8 + lr) * 2048 + kv0 + lcs,
             Vl + ci * 512);
    }
    __syncthreads();

    // S = Q K^T  (rows=q, cols=kv)
    f32x4 s[4] = {};
#pragma unroll
    for (int kk = 0; kk < 2; ++kk) {
      const int col = (kk * 32 + g * 8) ^ swr;
#pragma unroll
      for (int f = 0; f < 4; ++f) {
        short8 kf = *(const short8*)(Kl + (f * 16 + c) * 64 + col);
        s[f] = __builtin_amdgcn_mfma_f32_16x16x32_bf16(qf[kk], kf, s[f], 0, 0, 0);
      }
    }

    // scale + causal mask + online softmax (rows r: q = qb + g*4 + r)
    float pr[4][4];
#pragma unroll
    for (int r = 0; r < 4; ++r) {
      const int qi = qb + g * 4 + r;
      float mx = -1e30f;
#pragma unroll
      for (int f = 0; f < 4; ++f) {
        float sv = s[f][r] * 0.125f;
        if (kv0 + f * 16 + c > qi) sv = -1e30f;
        pr[f][r] = sv;
        mx = fmaxf(mx, sv);
      }
#pragma unroll
      for (int msk = 1; msk < 16; msk <<= 1)
        mx = fmaxf(mx, __shfl_xor(mx, msk, 64));
      const float mn = fmaxf(mrow[r], mx);
      const float al = __expf(mrow[r] - mn);
      float rs = 0.f;
#pragma unroll
      for (int f = 0; f < 4; ++f) {
        float p = __expf(pr[f][r] - mn);
        pr[f][r] = p;
        rs += p;
      }
#pragma unroll
      for (int msk = 1; msk < 16; msk <<= 1) rs += __shfl_xor(rs, msk, 64);
      lrow[r] = lrow[r] * al + rs;
      mrow[r] = mn;
#pragma unroll
      for (int fd = 0; fd < 4; ++fd) po[fd][r] *= al;
    }

    // P (C/D layout) -> per-wave LDS [16][72] -> A-fragment layout
#pragma unroll
    for (int f = 0; f < 4; ++f)
#pragma unroll
      for (int r = 0; r < 4; ++r)
        pw[(g * 4 + r) * 72 + f * 16 + c] = f2bf(pr[f][r]);

    // O += P V   (V in Vt layout [d][kv] -> B-fragment k-contiguous)
#pragma unroll
    for (int kk = 0; kk < 2; ++kk) {
      short8 pa = *(const short8*)(pw + c * 72 + kk * 32 + g * 8);
      const int col = (kk * 32 + g * 8) ^ swr;
#pragma unroll
      for (int fd = 0; fd < 4; ++fd) {
        short8 vf = *(const short8*)(Vl + (fd * 16 + c) * 64 + col);
        po[fd] = __builtin_amdgcn_mfma_f32_16x16x32_bf16(pa, vf, po[fd], 0, 0, 0);
      }
    }
    __syncthreads();
  }

#pragma unroll
  for (int fd = 0; fd < 4; ++fd) {
#pragma unroll
    for (int r = 0; r < 4; ++r) {
      const float ov = po[fd][r] / lrow[r];
      const int trow = qb + g * 4 + r;
      Oc[(size_t)(b * 2048 + trow) * 1024 + h * 64 + fd * 16 + c] = f2bf(ov);
    }
  }
}

// ---------- launch ----------
extern "C" void kernel_launch(void* const* d_in, const int* in_sizes, int n_in,
                              void* d_out, int out_size, void* d_ws,
                              size_t ws_size, hipStream_t stream) {
  const float* x = (const float*)d_in[0];
  const float* Wq = (const float*)d_in[1];
  const float* Wk = (const float*)d_in[2];
  const float* Wv = (const float*)d_in[3];
  const float* Wo = (const float*)d_in[4];
  float* out = (float*)d_out;

  char* ws = (char*)d_ws;
  unsigned short* xb   = (unsigned short*)ws;                       // 16 MB
  unsigned short* Qb   = (unsigned short*)(ws + (size_t)(16u << 20));  // 16 MB
  unsigned short* Attn = (unsigned short*)(ws + (size_t)(32u << 20));  // 16 MB
  unsigned short* Wcat = (unsigned short*)(ws + (size_t)(48u << 20));  // 2.25 MB
  unsigned short* Wot  = (unsigned short*)(ws + (size_t)(48u << 20) + 2359296);
  unsigned short* Kb   = (unsigned short*)(ws + (size_t)(48u << 20) + 2359296 + 2097152);
  unsigned short* Vtb  = (unsigned short*)(ws + (size_t)(48u << 20) + 2359296 + 2097152 + 1048576);

  // 1) casts / transposed-weight panels
  cast_x_bf16<<<8192, 256, 0, stream>>>((const float4*)x, (ushort4*)xb, 2097152);
  transpose_cvt<<<dim3(32, 32), dim3(32, 8), 0, stream>>>(Wq, Wcat, 1024, 1024);
  transpose_cvt<<<dim3(2, 32), dim3(32, 8), 0, stream>>>(Wk, Wcat + 1024 * 1024, 1024, 64);
  transpose_cvt<<<dim3(2, 32), dim3(32, 8), 0, stream>>>(Wv, Wcat + 1088 * 1024, 1024, 64);
  transpose_cvt<<<dim3(32, 32), dim3(32, 8), 0, stream>>>(Wo, Wot, 1024, 1024);

  // 2) fused QKV GEMM: [8192][1024] x [1152][1024]^T
  gemm_bt<0><<<dim3(9, 64), 256, 0, stream>>>(xb, Wcat, Qb, Kb, Vtb, nullptr,
                                              1152, 1024);

  // 3) causal MQA flash attention
  attn_mqa<<<dim3(32, 16, 4), 256, 0, stream>>>(Qb, Kb, Vtb, Attn);

  // 4) output projection: [8192][1024] x [1024][1024]^T -> fp32 d_out
  gemm_bt<1><<<dim3(8, 64), 256, 0, stream>>>(Attn, Wot, nullptr, nullptr,
                                              nullptr, out, 1024, 1024);
}

// Round 2
// 196.492 us; speedup vs baseline: 1.5971x; 1.5971x over previous
//
#include <hip/hip_runtime.h>

typedef __attribute__((ext_vector_type(8))) short short8;
typedef __attribute__((ext_vector_type(4))) float f32x4;

// ---------- helpers ----------
__device__ __forceinline__ unsigned short f2bf(float f) {
  unsigned u = __builtin_bit_cast(unsigned, f);
  u += 0x7fffu + ((u >> 16) & 1u);   // RNE
  return (unsigned short)(u >> 16);
}

#define GLDS16(g, l)                                                          \
  __builtin_amdgcn_global_load_lds(                                           \
      (const __attribute__((address_space(1))) void*)(g),                     \
      (__attribute__((address_space(3))) void*)(l), 16, 0, 0)

// Q pre-scale: HEAD_DIM^-0.5 * log2(e), so softmax uses exp2 directly.
#define QSCALE 0.18033688011112042f

// ---------- cast x (fp32 -> bf16), vectorized ----------
__global__ void cast_x_bf16(const float4* __restrict__ in,
                            ushort4* __restrict__ out, int n4) {
  int i = blockIdx.x * blockDim.x + threadIdx.x;
  if (i >= n4) return;
  float4 v = in[i];
  ushort4 o;
  o.x = f2bf(v.x); o.y = f2bf(v.y); o.z = f2bf(v.z); o.w = f2bf(v.w);
  out[i] = o;
}

// ---------- fused transpose+convert of all weights (one launch) ----------
// z=0: Wq [1024][1024] -> Wcat[0..]; z=1: Wo -> Wot; z=2: Wk,Wv [1024][64].
__global__ void transpose_cvt_all(const float* __restrict__ Wq,
                                  const float* __restrict__ Wk,
                                  const float* __restrict__ Wv,
                                  const float* __restrict__ Wo,
                                  unsigned short* __restrict__ Wcat,
                                  unsigned short* __restrict__ Wot) {
  __shared__ float tile[32][33];
  const int z = blockIdx.z;
  int bx = blockIdx.x;
  const float* in;
  unsigned short* out;
  int N;
  if (z == 0)      { in = Wq; out = Wcat;               N = 1024; }
  else if (z == 1) { in = Wo; out = Wot;                N = 1024; }
  else {
    if (bx < 2)      { in = Wk; out = Wcat + 1024 * 1024; N = 64; }
    else if (bx < 4) { in = Wv; out = Wcat + 1088 * 1024; N = 64; bx -= 2; }
    else return;
  }
  const int K = 1024;
  const int n0 = bx * 32, k0 = blockIdx.y * 32;
  const int tx = threadIdx.x, ty = threadIdx.y;  // block (32,8)
#pragma unroll
  for (int i = 0; i < 4; ++i)
    tile[ty + 8 * i][tx] = in[(size_t)(k0 + ty + 8 * i) * N + n0 + tx];
  __syncthreads();
#pragma unroll
  for (int i = 0; i < 4; ++i)
    out[(size_t)(n0 + ty + 8 * i) * K + k0 + tx] = f2bf(tile[tx][ty + 8 * i]);
}

// ---------- GEMM: C[M][N] = A[M][K](bf16) * Bt[N][K](bf16)^T ----------
// m97 structure: 128x128 tile, BK=64, 4 waves (2x2 of 64x64), global_load_lds w=16.
// EPI==0: QKV epilogue (col<1024 -> Q bf16 *QSCALE; col<1088 -> K bf16 [row][64];
//         else V TRANSPOSED bf16 [b][d][t]).  EPI==1: plain fp32 C.
template <int EPI>
__global__ __launch_bounds__(256) void gemm_bt(
    const unsigned short* __restrict__ A, const unsigned short* __restrict__ Bt,
    unsigned short* __restrict__ Cq, unsigned short* __restrict__ Ck,
    unsigned short* __restrict__ Cv, float* __restrict__ Cf, int N, int K) {
  __shared__ __align__(16) unsigned short As[128 * 64];
  __shared__ __align__(16) unsigned short Bs[128 * 64];
  const int tid = threadIdx.x;
  const int w = tid >> 6, lane = tid & 63;
  const int m0 = blockIdx.y * 128, n0 = blockIdx.x * 128;
  const int wm = (w >> 1) * 64, wn = (w & 1) * 64;
  const int g = lane >> 4, c = lane & 15;
  const int lr = lane >> 3, lc = (lane & 7) * 8;

  f32x4 acc[4][4] = {};

  for (int k0 = 0; k0 < K; k0 += 64) {
#pragma unroll
    for (int i = 0; i < 4; ++i) {
      int ci = w * 4 + i;  // 1KB chunk: rows 8ci..8ci+7
      GLDS16(A + (size_t)(m0 + ci * 8 + lr) * K + k0 + lc, As + ci * 512);
      GLDS16(Bt + (size_t)(n0 + ci * 8 + lr) * K + k0 + lc, Bs + ci * 512);
    }
    __syncthreads();
#pragma unroll
    for (int kk = 0; kk < 2; ++kk) {
      const int col = kk * 32 + g * 8;
      short8 av[4], bv[4];
#pragma unroll
      for (int mi = 0; mi < 4; ++mi)
        av[mi] = *(const short8*)(As + (wm + mi * 16 + c) * 64 + col);
#pragma unroll
      for (int ni = 0; ni < 4; ++ni)
        bv[ni] = *(const short8*)(Bs + (wn + ni * 16 + c) * 64 + col);
#pragma unroll
      for (int mi = 0; mi < 4; ++mi)
#pragma unroll
        for (int ni = 0; ni < 4; ++ni)
          acc[mi][ni] = __builtin_amdgcn_mfma_f32_16x16x32_bf16(
              av[mi], bv[ni], acc[mi][ni], 0, 0, 0);
    }
    __syncthreads();
  }

#pragma unroll
  for (int mi = 0; mi < 4; ++mi) {
#pragma unroll
    for (int ni = 0; ni < 4; ++ni) {
      f32x4 a = acc[mi][ni];
      const int col = n0 + wn + ni * 16 + c;
#pragma unroll
      for (int r = 0; r < 4; ++r) {
        const int row = m0 + wm + mi * 16 + g * 4 + r;
        float v = a[r];
        if (EPI == 0) {
          if (col < 1024)
            Cq[(size_t)row * 1024 + col] = f2bf(v * QSCALE);
          else if (col < 1088)
            Ck[(size_t)row * 64 + (col - 1024)] = f2bf(v);
          else  // V transposed: [b][d][t]
            Cv[((size_t)(row >> 11) * 64 + (col - 1088)) * 2048 + (row & 2047)] =
                f2bf(v);
        } else {
          Cf[(size_t)row * N + col] = v;
        }
      }
    }
  }
}

// ---------- causal multi-query flash attention, v2 ----------
// grid (16 qtile-pairs, 8 head-pairs, 4 batch), 512 thr = 8 waves.
// Waves 0-3 -> head hp*2, waves 4-7 -> head hp*2+1 (share staged K/V).
// Each block processes q-tiles {i, 31-i} -> exactly 33 KV iterations (balanced).
// K/V double-buffered via global_load_lds (stage-before-compute, 1 barrier/iter).
// K/V LDS XOR-swizzled (pre-swizzled global source + swizzled ds_read).
__global__ __launch_bounds__(512, 4) void attn_mqa(
    const unsigned short* __restrict__ Q, const unsigned short* __restrict__ Kb,
    const unsigned short* __restrict__ Vt, unsigned short* __restrict__ Oc) {
  __shared__ __align__(16) unsigned short Kl[2][64 * 64];
  __shared__ __align__(16) unsigned short Vl[2][64 * 64];
  __shared__ __align__(16) unsigned short Pl[8][16 * 72];
  const int tid = threadIdx.x;
  const int w = tid >> 6, lane = tid & 63;
  const int pairi = blockIdx.x;   // 0..15
  const int hp = blockIdx.y;      // 0..7
  const int b = blockIdx.z;       // 0..3
  const int h = hp * 2 + (w >> 2);
  const int wq = w & 3;
  const int g = lane >> 4, c = lane & 15;
  const int swr = (c & 7) * 8;                    // read-side xor (shorts)
  const int srow = tid >> 3;                      // staging row 0..63
  const int scs = ((tid & 7) ^ (srow & 7)) * 8;   // swizzled source col
  const unsigned short* Kbase = Kb + (size_t)b * 2048 * 64;
  const unsigned short* Vbase = Vt + (size_t)b * 64 * 2048;
  unsigned short* pw = Pl[w];

#pragma unroll 1
  for (int half = 0; half < 2; ++half) {
    const int qt = half ? (31 - pairi) : pairi;
    const int qb = qt * 64 + wq * 16;   // this wave's first q row (global t)

    // Q fragments (A-operand: row=c, k=g*8+j), pre-scaled by QSCALE
    short8 qf[2];
#pragma unroll
    for (int kk = 0; kk < 2; ++kk)
      qf[kk] = *(const short8*)(Q + (size_t)(b * 2048 + qb + c) * 1024 +
                                h * 64 + kk * 32 + g * 8);

    f32x4 po[4] = {};
    float mrow[4], lrow[4];
#pragma unroll
    for (int r = 0; r < 4; ++r) { mrow[r] = -1e30f; lrow[r] = 0.f; }

    // prologue: stage tile 0 into buf 0
    GLDS16(Kbase + (size_t)srow * 64 + scs, &Kl[0][0] + tid * 8);
    GLDS16(Vbase + (size_t)srow * 2048 + scs, &Vl[0][0] + tid * 8);
    int cur = 0;

    for (int it = 0; it <= qt; ++it) {
      __syncthreads();  // drains vmcnt: buf[cur] ready; prev reads of cur^1 done

      if (it < qt) {    // prefetch next tile into cur^1 (overlaps compute)
        const int kvn = (it + 1) * 64;
        GLDS16(Kbase + (size_t)(kvn + srow) * 64 + scs, &Kl[cur ^ 1][0] + tid * 8);
        GLDS16(Vbase + (size_t)srow * 2048 + kvn + scs, &Vl[cur ^ 1][0] + tid * 8);
      }

      const unsigned short* Kt = &Kl[cur][0];
      const unsigned short* Vc = &Vl[cur][0];
      const int kv0 = it * 64;

      // S = Q K^T (rows=q, cols=kv); Q already scaled into log2 domain
      f32x4 s[4] = {};
#pragma unroll
      for (int kk = 0; kk < 2; ++kk) {
        const int col = (kk * 32 + g * 8) ^ swr;
#pragma unroll
        for (int f = 0; f < 4; ++f) {
          short8 kf = *(const short8*)(Kt + (f * 16 + c) * 64 + col);
          s[f] = __builtin_amdgcn_mfma_f32_16x16x32_bf16(qf[kk], kf, s[f], 0, 0, 0);
        }
      }

      const bool diag = (it == qt);
      // online softmax per owned row r (q = qb + g*4 + r), exp2 domain
#pragma unroll
      for (int r = 0; r < 4; ++r) {
        float pr[4];
#pragma unroll
        for (int f = 0; f < 4; ++f) pr[f] = s[f][r];
        if (diag) {
          const int qi = qb + g * 4 + r;
#pragma unroll
          for (int f = 0; f < 4; ++f)
            if (kv0 + f * 16 + c > qi) pr[f] = -1e30f;
        }
        float mx = fmaxf(fmaxf(pr[0], pr[1]), fmaxf(pr[2], pr[3]));
#pragma unroll
        for (int msk = 1; msk < 16; msk <<= 1)
          mx = fmaxf(mx, __shfl_xor(mx, msk, 64));
        const float mn = fmaxf(mrow[r], mx);
        const float al = __builtin_amdgcn_exp2f(mrow[r] - mn);
        float rs = 0.f;
#pragma unroll
        for (int f = 0; f < 4; ++f) {
          const float p = __builtin_amdgcn_exp2f(pr[f] - mn);
          pr[f] = p;
          rs += p;
        }
#pragma unroll
        for (int msk = 1; msk < 16; msk <<= 1) rs += __shfl_xor(rs, msk, 64);
        lrow[r] = lrow[r] * al + rs;
        mrow[r] = mn;
#pragma unroll
        for (int fd = 0; fd < 4; ++fd) po[fd][r] *= al;
#pragma unroll
        for (int f = 0; f < 4; ++f)
          pw[(g * 4 + r) * 72 + f * 16 + c] = f2bf(pr[f]);
      }

      // O += P V  (V in [d][kv] layout -> B-fragment k-contiguous)
#pragma unroll
      for (int kk = 0; kk < 2; ++kk) {
        short8 pa = *(const short8*)(pw + c * 72 + kk * 32 + g * 8);
        const int col = (kk * 32 + g * 8) ^ swr;
#pragma unroll
        for (int fd = 0; fd < 4; ++fd) {
          short8 vf = *(const short8*)(Vc + (fd * 16 + c) * 64 + col);
          po[fd] = __builtin_amdgcn_mfma_f32_16x16x32_bf16(pa, vf, po[fd], 0, 0, 0);
        }
      }
      cur ^= 1;
    }

    __syncthreads();  // protect K/V LDS before next half's prologue stage

    // epilogue: O / l
#pragma unroll
    for (int r = 0; r < 4; ++r) {
      const float inv = 1.0f / lrow[r];
      const int trow = qb + g * 4 + r;
#pragma unroll
      for (int fd = 0; fd < 4; ++fd)
        Oc[(size_t)(b * 2048 + trow) * 1024 + h * 64 + fd * 16 + c] =
            f2bf(po[fd][r] * inv);
    }
  }
}

// ---------- launch ----------
extern "C" void kernel_launch(void* const* d_in, const int* in_sizes, int n_in,
                              void* d_out, int out_size, void* d_ws,
                              size_t ws_size, hipStream_t stream) {
  const float* x = (const float*)d_in[0];
  const float* Wq = (const float*)d_in[1];
  const float* Wk = (const float*)d_in[2];
  const float* Wv = (const float*)d_in[3];
  const float* Wo = (const float*)d_in[4];
  float* out = (float*)d_out;

  char* ws = (char*)d_ws;
  unsigned short* xb   = (unsigned short*)ws;                          // 16 MB
  unsigned short* Qb   = (unsigned short*)(ws + (size_t)(16u << 20));  // 16 MB
  unsigned short* Attn = (unsigned short*)(ws + (size_t)(32u << 20));  // 16 MB
  unsigned short* Wcat = (unsigned short*)(ws + (size_t)(48u << 20));  // 2.25 MB
  unsigned short* Wot  = (unsigned short*)(ws + (size_t)(48u << 20) + 2359296);
  unsigned short* Kb   = (unsigned short*)(ws + (size_t)(48u << 20) + 2359296 + 2097152);
  unsigned short* Vtb  = (unsigned short*)(ws + (size_t)(48u << 20) + 2359296 + 2097152 + 1048576);

  // 1) cast x, fused weight transposes (2 launches)
  cast_x_bf16<<<8192, 256, 0, stream>>>((const float4*)x, (ushort4*)xb, 2097152);
  transpose_cvt_all<<<dim3(32, 32, 3), dim3(32, 8), 0, stream>>>(Wq, Wk, Wv, Wo,
                                                                 Wcat, Wot);

  // 2) fused QKV GEMM: [8192][1024] x [1152][1024]^T
  gemm_bt<0><<<dim3(9, 64), 256, 0, stream>>>(xb, Wcat, Qb, Kb, Vtb, nullptr,
                                              1152, 1024);

  // 3) causal MQA flash attention (balanced tile pairs, 2 heads/block)
  attn_mqa<<<dim3(16, 8, 4), 512, 0, stream>>>(Qb, Kb, Vtb, Attn);

  // 4) output projection: [8192][1024] x [1024][1024]^T -> fp32 d_out
  gemm_bt<1><<<dim3(8, 64), 256, 0, stream>>>(Attn, Wot, nullptr, nullptr,
                                              nullptr, out, 1024, 1024);
}

// Round 4
// 153.818 us; speedup vs baseline: 2.0402x; 1.2774x over previous
//
#include <hip/hip_runtime.h>

typedef __attribute__((ext_vector_type(8))) short short8;
typedef __attribute__((ext_vector_type(4))) float f32x4;

// ---------- helpers ----------
__device__ __forceinline__ unsigned short f2bf(float f) {
  unsigned u = __builtin_bit_cast(unsigned, f);
  u += 0x7fffu + ((u >> 16) & 1u);   // RNE
  return (unsigned short)(u >> 16);
}
__device__ __forceinline__ unsigned pack_bf2(float lo, float hi) {
  return (unsigned)f2bf(lo) | ((unsigned)f2bf(hi) << 16);
}

#define GLDS16(g, l)                                                          \
  __builtin_amdgcn_global_load_lds(                                           \
      (const __attribute__((address_space(1))) void*)(g),                     \
      (__attribute__((address_space(3))) void*)(l), 16, 0, 0)

// Q pre-scale: HEAD_DIM^-0.5 * log2(e), so softmax uses exp2 directly.
#define QSCALE 0.18033688011112042f

// ---------- cast x (fp32 -> bf16), vectorized ----------
__global__ void cast_x_bf16(const float4* __restrict__ in,
                            ushort4* __restrict__ out, int n4) {
  int i = blockIdx.x * blockDim.x + threadIdx.x;
  if (i >= n4) return;
  float4 v = in[i];
  ushort4 o;
  o.x = f2bf(v.x); o.y = f2bf(v.y); o.z = f2bf(v.z); o.w = f2bf(v.w);
  out[i] = o;
}

// ---------- fused transpose+convert of all weights (one launch) ----------
__global__ void transpose_cvt_all(const float* __restrict__ Wq,
                                  const float* __restrict__ Wk,
                                  const float* __restrict__ Wv,
                                  const float* __restrict__ Wo,
                                  unsigned short* __restrict__ Wcat,
                                  unsigned short* __restrict__ Wot) {
  __shared__ float tile[32][33];
  const int z = blockIdx.z;
  int bx = blockIdx.x;
  const float* in;
  unsigned short* out;
  int N;
  if (z == 0)      { in = Wq; out = Wcat;               N = 1024; }
  else if (z == 1) { in = Wo; out = Wot;                N = 1024; }
  else {
    if (bx < 2)      { in = Wk; out = Wcat + 1024 * 1024; N = 64; }
    else if (bx < 4) { in = Wv; out = Wcat + 1088 * 1024; N = 64; bx -= 2; }
    else return;
  }
  const int K = 1024;
  const int n0 = bx * 32, k0 = blockIdx.y * 32;
  const int tx = threadIdx.x, ty = threadIdx.y;  // block (32,8)
#pragma unroll
  for (int i = 0; i < 4; ++i)
    tile[ty + 8 * i][tx] = in[(size_t)(k0 + ty + 8 * i) * N + n0 + tx];
  __syncthreads();
#pragma unroll
  for (int i = 0; i < 4; ++i)
    out[(size_t)(n0 + ty + 8 * i) * K + k0 + tx] = f2bf(tile[tx][ty + 8 * i]);
}

// ---------- GEMM: C[M][N] = A[M][K](bf16) * Bt[N][K](bf16)^T ----------
// m97 structure + bijective XCD-aware block swizzle (grid %8 == 0).
template <int EPI>
__global__ __launch_bounds__(256) void gemm_bt(
    const unsigned short* __restrict__ A, const unsigned short* __restrict__ Bt,
    unsigned short* __restrict__ Cq, unsigned short* __restrict__ Ck,
    unsigned short* __restrict__ Cv, float* __restrict__ Cf, int N, int K) {
  __shared__ __align__(16) unsigned short As[128 * 64];
  __shared__ __align__(16) unsigned short Bs[128 * 64];
  const int tid = threadIdx.x;
  const int w = tid >> 6, lane = tid & 63;
  // XCD swizzle: consecutive post-swizzle ids share an A-panel per XCD
  const int nwg = gridDim.x * gridDim.y;
  const int lid = blockIdx.y * gridDim.x + blockIdx.x;
  const int cpx = nwg >> 3;
  const int swz = (lid & 7) * cpx + (lid >> 3);
  const int m0 = (swz / gridDim.x) * 128, n0 = (swz % gridDim.x) * 128;
  const int wm = (w >> 1) * 64, wn = (w & 1) * 64;
  const int g = lane >> 4, c = lane & 15;
  const int lr = lane >> 3, lc = (lane & 7) * 8;

  f32x4 acc[4][4] = {};

  for (int k0 = 0; k0 < K; k0 += 64) {
#pragma unroll
    for (int i = 0; i < 4; ++i) {
      int ci = w * 4 + i;  // 1KB chunk: rows 8ci..8ci+7
      GLDS16(A + (size_t)(m0 + ci * 8 + lr) * K + k0 + lc, As + ci * 512);
      GLDS16(Bt + (size_t)(n0 + ci * 8 + lr) * K + k0 + lc, Bs + ci * 512);
    }
    __syncthreads();
#pragma unroll
    for (int kk = 0; kk < 2; ++kk) {
      const int col = kk * 32 + g * 8;
      short8 av[4], bv[4];
#pragma unroll
      for (int mi = 0; mi < 4; ++mi)
        av[mi] = *(const short8*)(As + (wm + mi * 16 + c) * 64 + col);
#pragma unroll
      for (int ni = 0; ni < 4; ++ni)
        bv[ni] = *(const short8*)(Bs + (wn + ni * 16 + c) * 64 + col);
#pragma unroll
      for (int mi = 0; mi < 4; ++mi)
#pragma unroll
        for (int ni = 0; ni < 4; ++ni)
          acc[mi][ni] = __builtin_amdgcn_mfma_f32_16x16x32_bf16(
              av[mi], bv[ni], acc[mi][ni], 0, 0, 0);
    }
    __syncthreads();
  }

#pragma unroll
  for (int mi = 0; mi < 4; ++mi) {
#pragma unroll
    for (int ni = 0; ni < 4; ++ni) {
      f32x4 a = acc[mi][ni];
      const int col = n0 + wn + ni * 16 + c;
#pragma unroll
      for (int r = 0; r < 4; ++r) {
        const int row = m0 + wm + mi * 16 + g * 4 + r;
        float v = a[r];
        if (EPI == 0) {
          if (col < 1024)
            Cq[(size_t)row * 1024 + col] = f2bf(v * QSCALE);
          else if (col < 1088)
            Ck[(size_t)row * 64 + (col - 1024)] = f2bf(v);
          else  // V transposed: [b][d][t]
            Cv[((size_t)(row >> 11) * 64 + (col - 1088)) * 2048 + (row & 2047)] =
                f2bf(v);
        } else {
          Cf[(size_t)row * N + col] = v;
        }
      }
    }
  }
}

// ---------- causal multi-query flash attention, v3 ----------
// Swapped QK^T (mfma(K,Q) -> S^T: lane owns q=lane&15, kv in regs) =>
// lane-local softmax, no shuffles in steady state; defer-max (THR=8, log2
// domain); row-sum l via ones-MFMA straight into po row layout.
__global__ __launch_bounds__(512, 4) void attn_mqa(
    const unsigned short* __restrict__ Q, const unsigned short* __restrict__ Kb,
    const unsigned short* __restrict__ Vt, unsigned short* __restrict__ Oc) {
  __shared__ __align__(16) unsigned short Kl[2][64 * 64];
  __shared__ __align__(16) unsigned short Vl[2][64 * 64];
  __shared__ __align__(16) unsigned short Pl[8][16 * 72];
  const int tid = threadIdx.x;
  const int w = tid >> 6, lane = tid & 63;
  const int pairi = blockIdx.x;   // 0..15
  const int hp = blockIdx.y;      // 0..7
  const int b = blockIdx.z;       // 0..3
  const int h = hp * 2 + (w >> 2);
  const int wq = w & 3;
  const int g = lane >> 4, c = lane & 15;
  const int swr = (c & 7) * 8;                    // read-side xor (shorts)
  const int srow = tid >> 3;                      // staging row 0..63
  const int scs = ((tid & 7) ^ (srow & 7)) * 8;   // swizzled source col
  const unsigned short* Kbase = Kb + (size_t)b * 2048 * 64;
  const unsigned short* Vbase = Vt + (size_t)b * 64 * 2048;
  unsigned short* pw = Pl[w];
  unsigned* pd = (unsigned*)pw;                   // dword view, row stride 36

  short8 ones;
#pragma unroll
  for (int j = 0; j < 8; ++j) ones[j] = (short)0x3F80;  // bf16 1.0

#pragma unroll 1
  for (int half = 0; half < 2; ++half) {
    const int qt = half ? (31 - pairi) : pairi;
    const int qb = qt * 64 + wq * 16;   // wave's first q row (global t)
    const int qi = qb + c;              // this lane's q row

    // Q fragments (B-operand: col=c, k=g*8+j), pre-scaled by QSCALE
    short8 qf[2];
#pragma unroll
    for (int kk = 0; kk < 2; ++kk)
      qf[kk] = *(const short8*)(Q + (size_t)(b * 2048 + qb + c) * 1024 +
                                h * 64 + kk * 32 + g * 8);

    f32x4 po[4] = {};
    f32x4 lac = {};
    float m = -1e30f;

    // prologue: stage tile 0 into buf 0
    GLDS16(Kbase + (size_t)srow * 64 + scs, &Kl[0][0] + tid * 8);
    GLDS16(Vbase + (size_t)srow * 2048 + scs, &Vl[0][0] + tid * 8);
    int cur = 0;

    for (int it = 0; it <= qt; ++it) {
      __syncthreads();  // buf[cur] staged; prev reads of cur^1 done

      if (it < qt) {    // prefetch next tile into cur^1 (overlaps compute)
        const int kvn = (it + 1) * 64;
        GLDS16(Kbase + (size_t)(kvn + srow) * 64 + scs, &Kl[cur ^ 1][0] + tid * 8);
        GLDS16(Vbase + (size_t)srow * 2048 + kvn + scs, &Vl[cur ^ 1][0] + tid * 8);
      }

      const unsigned short* Kt = &Kl[cur][0];
      const unsigned short* Vc = &Vl[cur][0];
      const int kv0 = it * 64;

      // S^T = K Q^T: s[f] rows = kv (f*16 + g*4 + r), cols = q (c)
      f32x4 s[4] = {};
#pragma unroll
      for (int kk = 0; kk < 2; ++kk) {
        const int col = (kk * 32 + g * 8) ^ swr;
#pragma unroll
        for (int f = 0; f < 4; ++f) {
          short8 kf = *(const short8*)(Kt + (f * 16 + c) * 64 + col);
          s[f] = __builtin_amdgcn_mfma_f32_16x16x32_bf16(kf, qf[kk], s[f], 0, 0, 0);
        }
      }

      if (it == qt) {   // causal mask, diagonal tile only
#pragma unroll
        for (int f = 0; f < 4; ++f)
#pragma unroll
          for (int r = 0; r < 4; ++r)
            if (kv0 + f * 16 + g * 4 + r > qi) s[f][r] = -1e30f;
      }

      // lane-local max over this lane's 16 kv values
      float pm = s[0][0];
#pragma unroll
      for (int f = 0; f < 4; ++f)
#pragma unroll
        for (int r = 0; r < 4; ++r) pm = fmaxf(pm, s[f][r]);

      // defer-max: rescale only when some row's max grew past THR=8 (log2)
      if (!__all(pm <= m + 8.0f)) {
        pm = fmaxf(pm, __shfl_xor(pm, 16, 64));
        pm = fmaxf(pm, __shfl_xor(pm, 32, 64));       // full max for q=c
        const float mn = fmaxf(m, pm);
        const float al = __builtin_amdgcn_exp2f(m - mn);  // alpha for q=c
        m = mn;
#pragma unroll
        for (int r = 0; r < 4; ++r) {
          const float ar = __shfl(al, g * 4 + r, 64);     // alpha for row g*4+r
          lac[r] *= ar;
#pragma unroll
          for (int fd = 0; fd < 4; ++fd) po[fd][r] *= ar;
        }
      }

      // P = exp2(S - m): pack pairs, bounce [q][kv] through per-wave LDS
#pragma unroll
      for (int f = 0; f < 4; ++f) {
        const float p0 = __builtin_amdgcn_exp2f(s[f][0] - m);
        const float p1 = __builtin_amdgcn_exp2f(s[f][1] - m);
        const float p2 = __builtin_amdgcn_exp2f(s[f][2] - m);
        const float p3 = __builtin_amdgcn_exp2f(s[f][3] - m);
        uint2 pk;
        pk.x = pack_bf2(p0, p1);
        pk.y = pack_bf2(p2, p3);
        *(uint2*)(pd + c * 36 + f * 8 + g * 2) = pk;
      }

      // O += P V ; l += P 1   (pa: A-frag P[q=c][kv=g*8+j+kk*32])
#pragma unroll
      for (int kk = 0; kk < 2; ++kk) {
        short8 pa = *(const short8*)(pw + c * 72 + kk * 32 + g * 8);
        lac = __builtin_amdgcn_mfma_f32_16x16x32_bf16(pa, ones, lac, 0, 0, 0);
        const int col = (kk * 32 + g * 8) ^ swr;
#pragma unroll
        for (int fd = 0; fd < 4; ++fd) {
          short8 vf = *(const short8*)(Vc + (fd * 16 + c) * 64 + col);
          po[fd] = __builtin_amdgcn_mfma_f32_16x16x32_bf16(pa, vf, po[fd], 0, 0, 0);
        }
      }
      cur ^= 1;
    }

    __syncthreads();  // protect K/V LDS before next half's prologue stage

    // epilogue: O / l  (l already in po row layout)
#pragma unroll
    for (int r = 0; r < 4; ++r) {
      const float inv = __builtin_amdgcn_rcpf(lac[r]);
      const int trow = qb + g * 4 + r;
#pragma unroll
      for (int fd = 0; fd < 4; ++fd)
        Oc[(size_t)(b * 2048 + trow) * 1024 + h * 64 + fd * 16 + c] =
            f2bf(po[fd][r] * inv);
    }
  }
}

// ---------- launch ----------
extern "C" void kernel_launch(void* const* d_in, const int* in_sizes, int n_in,
                              void* d_out, int out_size, void* d_ws,
                              size_t ws_size, hipStream_t stream) {
  const float* x = (const float*)d_in[0];
  const float* Wq = (const float*)d_in[1];
  const float* Wk = (const float*)d_in[2];
  const float* Wv = (const float*)d_in[3];
  const float* Wo = (const float*)d_in[4];
  float* out = (float*)d_out;

  char* ws = (char*)d_ws;
  unsigned short* xb   = (unsigned short*)ws;                          // 16 MB
  unsigned short* Qb   = (unsigned short*)(ws + (size_t)(16u << 20));  // 16 MB
  unsigned short* Attn = (unsigned short*)(ws + (size_t)(32u << 20));  // 16 MB
  unsigned short* Wcat = (unsigned short*)(ws + (size_t)(48u << 20));  // 2.25 MB
  unsigned short* Wot  = (unsigned short*)(ws + (size_t)(48u << 20) + 2359296);
  unsigned short* Kb   = (unsigned short*)(ws + (size_t)(48u << 20) + 2359296 + 2097152);
  unsigned short* Vtb  = (unsigned short*)(ws + (size_t)(48u << 20) + 2359296 + 2097152 + 1048576);

  // 1) cast x, fused weight transposes
  cast_x_bf16<<<8192, 256, 0, stream>>>((const float4*)x, (ushort4*)xb, 2097152);
  transpose_cvt_all<<<dim3(32, 32, 3), dim3(32, 8), 0, stream>>>(Wq, Wk, Wv, Wo,
                                                                 Wcat, Wot);

  // 2) fused QKV GEMM: [8192][1024] x [1152][1024]^T
  gemm_bt<0><<<dim3(9, 64), 256, 0, stream>>>(xb, Wcat, Qb, Kb, Vtb, nullptr,
                                              1152, 1024);

  // 3) causal MQA flash attention
  attn_mqa<<<dim3(16, 8, 4), 512, 0, stream>>>(Qb, Kb, Vtb, Attn);

  // 4) output projection: [8192][1024] x [1024][1024]^T -> fp32 d_out
  gemm_bt<1><<<dim3(8, 64), 256, 0, stream>>>(Attn, Wot, nullptr, nullptr,
                                              nullptr, out, 1024, 1024);
}